// Round 3
// baseline (463.280 us; speedup 1.0000x reference)
//
#include <hip/hip_runtime.h>
#include <math.h>

#define BATCH 2048
#define N_TIME 2048
#define INPUT_SIZE 28
#define OUTPUT_SIZE 7
#define N_S 4
#define PERIOD 7
#define EMBED 9
#define SEAS_LEN (N_TIME + PERIOD)       // 2055
#define W_COUNT 288                      // len(range(0, 2014, 7))
#define WB_COUNT (W_COUNT * BATCH)       // 589824
#define INS_COLS 67                      // 28 + 35 + 4
#define OUT0_SIZE (WB_COUNT * INS_COLS)  // 39,518,208
#define OUT1_SIZE (WB_COUNT * OUTPUT_SIZE) // 4,128,768
#define LEV_SIZE (BATCH * N_TIME)
#define SEAS_SIZE (BATCH * SEAS_LEN)

// Split of the window work:
//   kernel1 copy blocks: out0 cols j in [28,67) (X and S) + all of out1.
//     These depend only on X/S/Y -> run CONCURRENTLY with the scan on the
//     ~224 CUs the 32 scan blocks don't use.
//   kernel2: out0 cols j in [0,28) (y_in; needs levels/seasonal).
#define M0_COPY (WB_COUNT * 39)              // 23,003,136 (X+S cols)
#define M_COPY  (M0_COPY + OUT1_SIZE)        // 27,131,904
#define COPY_BLOCKS 480
#define GRID1 (32 + COPY_BLOCKS)
#define N_YIN (WB_COUNT * INPUT_SIZE)        // 16,515,072 = 64512*256

// ---------------------------------------------------------------------------
// Phase 1 scan: producer-consumer wave split (blocks 0..31) + concurrent
// window-copy blocks (32..511). 128 threads/block, 66.5 KB LDS -> 2 blocks/CU.
//   wave 0 (producer): software-pipelined recurrence. s_k = ns_{k-7} is known
//     7 steps early -> rbuf holds lsms*rcp(s); level update is ONE carried fma.
//   wave 1 (consumer): drains the finished tile (LDS transpose, coalesced
//     global stores) concurrently with the producer's next chunk.
// Sync = one raw s_barrier per chunk + lgkmcnt(0)-only fences (no vmcnt
// drain). Copy blocks never execute barriers (per-workgroup, no interaction).
// ---------------------------------------------------------------------------
struct ScanState {
    float lev, lsms, seas_sms, oma, oms;
    float sbuf[PERIOD];   // s_{g}..s_{g+6} at entry to step g
    float rbuf[PERIOD];   // lsms * rcp(s_{g+i})
    float yp, sp, rnlp, rnsp;  // pipeline: y_{g-1}, s_{g-1}, rcp(nl_{g-1}), rcp(ns_{g-2})
};

template<bool FIRST, bool LAST, bool PREF>
__device__ __forceinline__ void scan_chunk(
    int base, int l,
    const float* __restrict__ Yb,
    float (&cur)[64], float (&nxt)[64],
    float (*__restrict__ tl)[65], float (*__restrict__ ts)[65],
    ScanState& st)
{
    if (PREF) {
#pragma unroll
        for (int k = 0; k < 64; k += 4)
            *(float4*)&nxt[k] = *(const float4*)(Yb + base + 64 + k);
    }
    tl[l][0] = st.lev;                 // carry-in: levels col `base`
#pragma unroll
    for (int k = 0; k < 64; ++k) {
        if (!LAST || k < 63) {         // last chunk has 63 steps
            float y  = (k < 63) ? cur[k + 1] : nxt[0];
            float s0 = st.sbuf[0];
            // level: single dependent fma (all other operands steps-old)
            float nl = fmaf(st.oma, st.lev, y * st.rbuf[0]);
            st.lev = nl;
            tl[l][k + 1] = nl;
            // finish PREVIOUS step's seasonal (rcp latency hidden)
            if (!FIRST || k > 0) {
                float u  = st.yp * st.rnlp;
                float ns = fmaf(st.oms, st.sp, st.seas_sms * u);
                ts[l][k] = ns;                 // seasonal col base+7+k = ns_{g-1}
                st.sbuf[PERIOD - 1] = ns;      // s_{g+6}
                if (!FIRST || k > 1)
                    st.rbuf[PERIOD - 2] = st.lsms * st.rnsp;
                st.rnsp = __builtin_amdgcn_rcpf(ns);
            }
            float rnl = __builtin_amdgcn_rcpf(nl);   // consumed next step
#pragma unroll
            for (int q = 0; q < PERIOD - 1; ++q) st.sbuf[q] = st.sbuf[q + 1];
#pragma unroll
            for (int q = 0; q < PERIOD - 1; ++q) st.rbuf[q] = st.rbuf[q + 1];
            st.yp = y; st.sp = s0; st.rnlp = rnl;
        }
    }
    if (LAST) {                        // drain the pipeline: ns_{2046}
        float u  = st.yp * st.rnlp;
        float ns = fmaf(st.oms, st.sp, st.seas_sms * u);
        ts[l][63] = ns;                // seasonal col 2054
    }
    asm volatile("s_waitcnt lgkmcnt(0)" ::: "memory");
    __builtin_amdgcn_s_barrier();
}

__device__ __forceinline__ void drain_chunk(
    int base, int jr, int km, int r0,
    const float (*__restrict__ tl)[65], const float (*__restrict__ ts)[65],
    float* __restrict__ levels, float* __restrict__ seasonal)
{
    __builtin_amdgcn_s_barrier();      // wait for producer to finish this tile
    asm volatile("" ::: "memory");
#pragma unroll
    for (int j0 = 0; j0 < 64; j0 += 4) {
        int j = j0 + jr;               // tile row = local batch row
        float vl[4], vs[4];
#pragma unroll
        for (int i = 0; i < 4; ++i) { vl[i] = tl[j][km + i]; vs[i] = ts[j][km + i]; }
        float4 v4; v4.x = vl[0]; v4.y = vl[1]; v4.z = vl[2]; v4.w = vl[3];
        *(float4*)(levels + (size_t)(r0 + j) * N_TIME + base + km) = v4;
        float* srow = seasonal + (size_t)(r0 + j) * SEAS_LEN + base + 7 + km;
#pragma unroll
        for (int i = 0; i < 4; ++i) srow[i] = vs[i];
    }
    // reads must be complete before joining the next barrier (buffer reuse)
    asm volatile("s_waitcnt lgkmcnt(0)" ::: "memory");
}

__device__ __forceinline__ void copy_elem(
    unsigned g,
    const float* __restrict__ Y, const float* __restrict__ X,
    const float* __restrict__ S,
    float* __restrict__ out0, float* __restrict__ out1)
{
    if (g < M0_COPY) {                 // out0 cols 28..66 (X then S)
        unsigned wb = g / 39u;
        int jj = (int)(g - wb * 39u);
        int w  = (int)(wb >> 11);
        int b  = (int)(wb & (BATCH - 1));
        float v = (jj < 35) ? X[b * N_TIME + w * 7 + jj]
                            : S[b * N_S + (jj - 35)];
        out0[(size_t)wb * 67u + 28u + (unsigned)jj] = v;
    } else {                           // out1
        unsigned e  = g - M0_COPY;
        unsigned wb = e / 7u;
        int m  = (int)(e - wb * 7u);
        int w  = (int)(wb >> 11);
        int b  = (int)(wb & (BATCH - 1));
        out1[e] = Y[b * N_TIME + w * 7 + INPUT_SIZE + m];
    }
}

__global__ __launch_bounds__(128) void es_scan_plus(
    const float* __restrict__ Y, const int* __restrict__ idxs,
    const float* __restrict__ emb, const float* __restrict__ X,
    const float* __restrict__ S,
    float* __restrict__ levels, float* __restrict__ seasonal,
    float* __restrict__ out0, float* __restrict__ out1)
{
    __shared__ float tl[2][64][65];
    __shared__ float ts[2][64][65];
    const int tid = threadIdx.x;
    const int l   = tid & 63;

    if (blockIdx.x >= 32) {
        // ---------------- window-copy blocks (no barriers, grid-stride) ----------
        const unsigned stride = COPY_BLOCKS * 128;
        unsigned g0 = (blockIdx.x - 32) * 128 + tid;
#pragma unroll 1
        for (unsigned g = g0; g < M_COPY; g += stride * 4) {
#pragma unroll
            for (int u = 0; u < 4; ++u) {
                unsigned gg = g + (unsigned)u * stride;
                if (gg < M_COPY) copy_elem(gg, Y, X, S, out0, out1);
            }
        }
        return;
    }

    const int r0 = blockIdx.x * 64;
    if (tid < 64) {
        // ---------------- producer wave: the recurrence ----------------
        const int b = r0 + l;
        const float* Yb = Y + (size_t)b * N_TIME;
        const float* e  = emb + (size_t)idxs[b] * EMBED;
        ScanState st;
        st.lsms     = 1.0f / (1.0f + __expf(-e[0]));
        st.seas_sms = 1.0f / (1.0f + __expf(-e[1]));
        st.oma = 1.0f - st.lsms;
        st.oms = 1.0f - st.seas_sms;
        float is[PERIOD];
#pragma unroll
        for (int j = 0; j < PERIOD; ++j) is[j] = __expf(e[2 + j]);
        st.lev = Yb[0] / is[0];

        float* seab = seasonal + (size_t)b * SEAS_LEN;
#pragma unroll
        for (int j = 0; j < PERIOD; ++j) seab[j] = is[j];
        ts[0][l][0] = is[0];           // seasonal col 7 (= "ns_{-1}") for chunk 0
#pragma unroll
        for (int j = 0; j < PERIOD; ++j) st.sbuf[j] = is[(j + 1) % PERIOD];
#pragma unroll
        for (int j = 0; j < PERIOD; ++j)
            st.rbuf[j] = st.lsms * __builtin_amdgcn_rcpf(st.sbuf[j]);
        st.yp = 0.0f; st.sp = 1.0f; st.rnlp = 1.0f; st.rnsp = 1.0f;

        float ya[64], yb2[64];
#pragma unroll
        for (int k = 0; k < 64; k += 4)
            *(float4*)&ya[k] = *(const float4*)(Yb + k);

        scan_chunk<true,  false, true >(0, l, Yb, ya, yb2, tl[0], ts[0], st);
#pragma unroll 1
        for (int cc = 0; cc < 15; ++cc) {
            scan_chunk<false, false, true>(64  + cc * 128, l, Yb, yb2, ya, tl[1], ts[1], st);
            scan_chunk<false, false, true>(128 + cc * 128, l, Yb, ya, yb2, tl[0], ts[0], st);
        }
        scan_chunk<false, true,  false>(1984, l, Yb, yb2, ya, tl[1], ts[1], st);
    } else {
        // ---------------- consumer wave: transpose + coalesced stores ----------
        const int jr = l >> 4;
        const int km = (l & 15) * 4;
#pragma unroll 1
        for (int c = 0; c < 32; ++c)
            drain_chunk(c * 64, jr, km, r0, tl[c & 1], ts[c & 1], levels, seasonal);
    }
}

// ---------------------------------------------------------------------------
// Phase 2: y_in columns only (j < 28; needs levels/seasonal).
// Reads: Y and seasonal consecutive within each 28-run, levels broadcast.
// Stores: 28 consecutive floats per run (stride-67 rows) -> ~2-3 sectors/run.
// ---------------------------------------------------------------------------
__global__ __launch_bounds__(256) void es_windows_yin(
    const float* __restrict__ Y, const float* __restrict__ levels,
    const float* __restrict__ seasonal, float* __restrict__ out0)
{
    unsigned gid = blockIdx.x * 256 + threadIdx.x;
    unsigned wb = gid / 28u;
    int j  = (int)(gid - wb * 28u);
    int w  = (int)(wb >> 11);
    int b  = (int)(wb & (BATCH - 1));
    int t0 = w * 7;
    float y  = Y[b * N_TIME + t0 + j];
    float lv = levels[b * N_TIME + t0 + INPUT_SIZE - 1];
    float sv = seasonal[b * SEAS_LEN + t0 + j];
    out0[(size_t)wb * 67u + (unsigned)j] =
        __logf(y * __builtin_amdgcn_rcpf(lv * sv));
}

extern "C" void kernel_launch(void* const* d_in, const int* in_sizes, int n_in,
                              void* d_out, int out_size, void* d_ws, size_t ws_size,
                              hipStream_t stream) {
    const float* S    = (const float*)d_in[0];
    const float* Y    = (const float*)d_in[1];
    const float* X    = (const float*)d_in[2];
    const int*   idxs = (const int*)d_in[3];
    const float* emb  = (const float*)d_in[4];

    float* out      = (float*)d_out;
    float* out_ins  = out;                                    // (W,B,67)
    float* out_outs = out + OUT0_SIZE;                        // (W,B,7)
    float* levels   = out + OUT0_SIZE + OUT1_SIZE;            // (B,2048)
    float* seasonal = out + OUT0_SIZE + OUT1_SIZE + LEV_SIZE; // (B,2055)

    es_scan_plus<<<GRID1, 128, 0, stream>>>(
        Y, idxs, emb, X, S, levels, seasonal, out_ins, out_outs);

    es_windows_yin<<<N_YIN / 256, 256, 0, stream>>>(
        Y, levels, seasonal, out_ins);
}

// Round 4
// 349.140 us; speedup vs baseline: 1.3269x; 1.3269x over previous
//
#include <hip/hip_runtime.h>
#include <math.h>

#define BATCH 2048
#define N_TIME 2048
#define INPUT_SIZE 28
#define OUTPUT_SIZE 7
#define N_S 4
#define PERIOD 7
#define EMBED 9
#define SEAS_LEN (N_TIME + PERIOD)       // 2055
#define W_COUNT 288                      // len(range(0, 2014, 7))
#define WB_COUNT (W_COUNT * BATCH)       // 589824
#define INS_COLS 67                      // 28 + 35 + 4
#define OUT0_SIZE (WB_COUNT * INS_COLS)  // 39,518,208
#define OUT1_SIZE (WB_COUNT * OUTPUT_SIZE) // 4,128,768
#define LEV_SIZE (BATCH * N_TIME)
#define SEAS_SIZE (BATCH * SEAS_LEN)

// Work split:
//   kernel1 scan blocks (0..31): producer-consumer ES recurrence.
//   kernel1 copy blocks (32..511): out0 cols [28,67) (X,S) + all of out1 —
//     depends only on X/S/Y, runs concurrently on the CUs the scan leaves idle.
//   kernel2: out0 cols [0,28) (y_in; needs levels/seasonal).
#define M0_COPY (WB_COUNT * 39)              // 23,003,136 (X+S cols)
#define M_COPY  (M0_COPY + OUT1_SIZE)        // 27,131,904
#define COPY_BLOCKS 480
#define GRID1 (32 + COPY_BLOCKS)
#define N_YIN (WB_COUNT * INPUT_SIZE)        // 16,515,072 = 64512*256
#define CUNROLL 16

// ---------------------------------------------------------------------------
// Scan: producer wave = software-pipelined recurrence (s_k = ns_{k-7} known 7
// steps early -> level update is ONE carried fma); consumer wave = tile
// transpose + coalesced stores, concurrent with the next chunk's compute.
// Sync = one raw s_barrier per chunk + lgkmcnt(0)-only fences.
// __launch_bounds__(128, 1): min 1 wave/EU -> register budget up to 512.
//   ROUND-3 LESSON: without this the merged kernel allocated 132 VGPRs and
//   spilled the 128-float y double-buffer to scratch (16.1 MB of spill stores
//   visible in WRITE_SIZE). 4 waves/CU needed; even VGPR=512 allows that.
// ---------------------------------------------------------------------------
struct ScanState {
    float lev, lsms, seas_sms, oma, oms;
    float sbuf[PERIOD];   // s_{g}..s_{g+6} at entry to step g
    float rbuf[PERIOD];   // lsms * rcp(s_{g+i})
    float yp, sp, rnlp, rnsp;  // y_{g-1}, s_{g-1}, rcp(nl_{g-1}), rcp(ns_{g-2})
};

template<bool FIRST, bool LAST, bool PREF>
__device__ __forceinline__ void scan_chunk(
    int base, int l,
    const float* __restrict__ Yb,
    float (&cur)[64], float (&nxt)[64],
    float (*__restrict__ tl)[65], float (*__restrict__ ts)[65],
    ScanState& st)
{
    if (PREF) {
#pragma unroll
        for (int k = 0; k < 64; k += 4)
            *(float4*)&nxt[k] = *(const float4*)(Yb + base + 64 + k);
    }
    tl[l][0] = st.lev;                 // carry-in: levels col `base`
#pragma unroll
    for (int k = 0; k < 64; ++k) {
        if (!LAST || k < 63) {         // last chunk has 63 steps
            float y  = (k < 63) ? cur[k + 1] : nxt[0];
            float s0 = st.sbuf[0];
            float nl = fmaf(st.oma, st.lev, y * st.rbuf[0]);
            st.lev = nl;
            tl[l][k + 1] = nl;
            if (!FIRST || k > 0) {     // finish PREVIOUS step's seasonal
                float u  = st.yp * st.rnlp;
                float ns = fmaf(st.oms, st.sp, st.seas_sms * u);
                ts[l][k] = ns;                 // seasonal col base+7+k = ns_{g-1}
                st.sbuf[PERIOD - 1] = ns;
                if (!FIRST || k > 1)
                    st.rbuf[PERIOD - 2] = st.lsms * st.rnsp;
                st.rnsp = __builtin_amdgcn_rcpf(ns);
            }
            float rnl = __builtin_amdgcn_rcpf(nl);   // consumed next step
#pragma unroll
            for (int q = 0; q < PERIOD - 1; ++q) st.sbuf[q] = st.sbuf[q + 1];
#pragma unroll
            for (int q = 0; q < PERIOD - 1; ++q) st.rbuf[q] = st.rbuf[q + 1];
            st.yp = y; st.sp = s0; st.rnlp = rnl;
        }
    }
    if (LAST) {                        // drain pipeline: ns_{2046}
        float u  = st.yp * st.rnlp;
        float ns = fmaf(st.oms, st.sp, st.seas_sms * u);
        ts[l][63] = ns;                // seasonal col 2054
    }
    asm volatile("s_waitcnt lgkmcnt(0)" ::: "memory");
    __builtin_amdgcn_s_barrier();
}

__device__ __forceinline__ void drain_chunk(
    int base, int jr, int km, int r0,
    const float (*__restrict__ tl)[65], const float (*__restrict__ ts)[65],
    float* __restrict__ levels, float* __restrict__ seasonal)
{
    __builtin_amdgcn_s_barrier();      // wait for producer to finish this tile
    asm volatile("" ::: "memory");
#pragma unroll
    for (int j0 = 0; j0 < 64; j0 += 4) {
        int j = j0 + jr;               // tile row = local batch row
        float vl[4], vs[4];
#pragma unroll
        for (int i = 0; i < 4; ++i) { vl[i] = tl[j][km + i]; vs[i] = ts[j][km + i]; }
        float4 v4; v4.x = vl[0]; v4.y = vl[1]; v4.z = vl[2]; v4.w = vl[3];
        *(float4*)(levels + (size_t)(r0 + j) * N_TIME + base + km) = v4;
        float* srow = seasonal + (size_t)(r0 + j) * SEAS_LEN + base + 7 + km;
#pragma unroll
        for (int i = 0; i < 4; ++i) srow[i] = vs[i];
    }
    asm volatile("s_waitcnt lgkmcnt(0)" ::: "memory");
}

// gather one copy element: src value + dst pointer
__device__ __forceinline__ void copy_addr(
    unsigned g,
    const float* __restrict__ Y, const float* __restrict__ X,
    const float* __restrict__ S,
    float* __restrict__ out0, float* __restrict__ out1,
    const float*& src, float*& dst)
{
    if (g < M0_COPY) {                 // out0 cols 28..66 (X then S)
        unsigned wb = g / 39u;
        int jj = (int)(g - wb * 39u);
        int w  = (int)(wb >> 11);
        int b  = (int)(wb & (BATCH - 1));
        src = (jj < 35) ? &X[b * N_TIME + w * 7 + jj]
                        : &S[b * N_S + (jj - 35)];
        dst = &out0[(size_t)wb * 67u + 28u + (unsigned)jj];
    } else {                           // out1
        unsigned e  = g - M0_COPY;
        unsigned wb = e / 7u;
        int m  = (int)(e - wb * 7u);
        int w  = (int)(wb >> 11);
        int b  = (int)(wb & (BATCH - 1));
        src = &Y[b * N_TIME + w * 7 + INPUT_SIZE + m];
        dst = &out1[e];
    }
}

__global__ __launch_bounds__(128, 1) void es_scan_plus(
    const float* __restrict__ Y, const int* __restrict__ idxs,
    const float* __restrict__ emb, const float* __restrict__ X,
    const float* __restrict__ S,
    float* __restrict__ levels, float* __restrict__ seasonal,
    float* __restrict__ out0, float* __restrict__ out1)
{
    __shared__ float tl[2][64][65];
    __shared__ float ts[2][64][65];
    const int tid = threadIdx.x;
    const int l   = tid & 63;

    if (blockIdx.x >= 32) {
        // ------- copy blocks: 16-deep gather/scatter (64 B in flight/thread,
        // ~4 MB chip-wide -> latency fully covered; round-3's unroll-4 was
        // Little's-law limited to ~1.4 TB/s) -------
        const unsigned stride = COPY_BLOCKS * 128;
        unsigned g = (blockIdx.x - 32) * 128 + tid;
#pragma unroll 1
        for (; g + (CUNROLL - 1) * stride < M_COPY; g += stride * CUNROLL) {
            const float* src[CUNROLL]; float* dst[CUNROLL]; float v[CUNROLL];
#pragma unroll
            for (int u = 0; u < CUNROLL; ++u)
                copy_addr(g + (unsigned)u * stride, Y, X, S, out0, out1, src[u], dst[u]);
#pragma unroll
            for (int u = 0; u < CUNROLL; ++u) v[u] = *src[u];
#pragma unroll
            for (int u = 0; u < CUNROLL; ++u) *dst[u] = v[u];
        }
#pragma unroll 1
        for (; g < M_COPY; g += stride) {
            const float* src; float* dst;
            copy_addr(g, Y, X, S, out0, out1, src, dst);
            *dst = *src;
        }
        return;
    }

    const int r0 = blockIdx.x * 64;
    if (tid < 64) {
        // ---------------- producer wave: the recurrence ----------------
        const int b = r0 + l;
        const float* Yb = Y + (size_t)b * N_TIME;
        const float* e  = emb + (size_t)idxs[b] * EMBED;
        ScanState st;
        st.lsms     = 1.0f / (1.0f + __expf(-e[0]));
        st.seas_sms = 1.0f / (1.0f + __expf(-e[1]));
        st.oma = 1.0f - st.lsms;
        st.oms = 1.0f - st.seas_sms;
        float is[PERIOD];
#pragma unroll
        for (int j = 0; j < PERIOD; ++j) is[j] = __expf(e[2 + j]);
        st.lev = Yb[0] / is[0];

        float* seab = seasonal + (size_t)b * SEAS_LEN;
#pragma unroll
        for (int j = 0; j < PERIOD; ++j) seab[j] = is[j];
        ts[0][l][0] = is[0];           // seasonal col 7 (= "ns_{-1}") for chunk 0
#pragma unroll
        for (int j = 0; j < PERIOD; ++j) st.sbuf[j] = is[(j + 1) % PERIOD];
#pragma unroll
        for (int j = 0; j < PERIOD; ++j)
            st.rbuf[j] = st.lsms * __builtin_amdgcn_rcpf(st.sbuf[j]);
        st.yp = 0.0f; st.sp = 1.0f; st.rnlp = 1.0f; st.rnsp = 1.0f;

        float ya[64], yb2[64];
#pragma unroll
        for (int k = 0; k < 64; k += 4)
            *(float4*)&ya[k] = *(const float4*)(Yb + k);

        scan_chunk<true,  false, true >(0, l, Yb, ya, yb2, tl[0], ts[0], st);
#pragma unroll 1
        for (int cc = 0; cc < 15; ++cc) {
            scan_chunk<false, false, true>(64  + cc * 128, l, Yb, yb2, ya, tl[1], ts[1], st);
            scan_chunk<false, false, true>(128 + cc * 128, l, Yb, ya, yb2, tl[0], ts[0], st);
        }
        scan_chunk<false, true,  false>(1984, l, Yb, yb2, ya, tl[1], ts[1], st);
    } else {
        // ---------------- consumer wave: transpose + coalesced stores ----------
        const int jr = l >> 4;
        const int km = (l & 15) * 4;
#pragma unroll 1
        for (int c = 0; c < 32; ++c)
            drain_chunk(c * 64, jr, km, r0, tl[c & 1], ts[c & 1], levels, seasonal);
    }
}

// ---------------------------------------------------------------------------
// Phase 2: y_in columns only (j < 28; needs levels/seasonal).
// ---------------------------------------------------------------------------
__global__ __launch_bounds__(256) void es_windows_yin(
    const float* __restrict__ Y, const float* __restrict__ levels,
    const float* __restrict__ seasonal, float* __restrict__ out0)
{
    unsigned gid = blockIdx.x * 256 + threadIdx.x;
    unsigned wb = gid / 28u;
    int j  = (int)(gid - wb * 28u);
    int w  = (int)(wb >> 11);
    int b  = (int)(wb & (BATCH - 1));
    int t0 = w * 7;
    float y  = Y[b * N_TIME + t0 + j];
    float lv = levels[b * N_TIME + t0 + INPUT_SIZE - 1];
    float sv = seasonal[b * SEAS_LEN + t0 + j];
    out0[(size_t)wb * 67u + (unsigned)j] =
        __logf(y * __builtin_amdgcn_rcpf(lv * sv));
}

extern "C" void kernel_launch(void* const* d_in, const int* in_sizes, int n_in,
                              void* d_out, int out_size, void* d_ws, size_t ws_size,
                              hipStream_t stream) {
    const float* S    = (const float*)d_in[0];
    const float* Y    = (const float*)d_in[1];
    const float* X    = (const float*)d_in[2];
    const int*   idxs = (const int*)d_in[3];
    const float* emb  = (const float*)d_in[4];

    float* out      = (float*)d_out;
    float* out_ins  = out;                                    // (W,B,67)
    float* out_outs = out + OUT0_SIZE;                        // (W,B,7)
    float* levels   = out + OUT0_SIZE + OUT1_SIZE;            // (B,2048)
    float* seasonal = out + OUT0_SIZE + OUT1_SIZE + LEV_SIZE; // (B,2055)

    es_scan_plus<<<GRID1, 128, 0, stream>>>(
        Y, idxs, emb, X, S, levels, seasonal, out_ins, out_outs);

    es_windows_yin<<<N_YIN / 256, 256, 0, stream>>>(
        Y, levels, seasonal, out_ins);
}